// Round 18
// baseline (713.385 us; speedup 1.0000x reference)
//
#include <hip/hip_runtime.h>
#include <hip/hip_bf16.h>

// Model dims
#define VOCAB 21128
#define EMBED 768
#define DMODEL 256
#define HID 100
#define NTAGS 21
#define BB 32
#define TT 256
#define NTOK (BB*TT)   // 8192 tokens, token index i = t*BB + b

typedef float f32x4 __attribute__((ext_vector_type(4)));
typedef unsigned int u32x4 __attribute__((ext_vector_type(4)));
typedef short s16x8 __attribute__((ext_vector_type(8)));

__device__ __forceinline__ float sigm(float x) { return 1.0f / (1.0f + __expf(-x)); }
__device__ __forceinline__ float tanh_(float x) { return 2.0f / (1.0f + __expf(-2.0f * x)) - 1.0f; }

__device__ __forceinline__ unsigned int bfr(float x) {
    unsigned int u = __float_as_uint(x);
    return (u + 0x7fffu + ((u >> 16) & 1u)) >> 16;
}
__device__ __forceinline__ unsigned int bfpack(float lo, float hi) {
    return (bfr(hi) << 16) | bfr(lo);
}
__device__ __forceinline__ s16x8 asfrag(u32x4 v) {
    union { u32x4 u; s16x8 s; } x; x.u = v; return x.s;
}

// Raw barrier: fence LDS only; vmem rides across.
#define BAR() do { \
    asm volatile("s_waitcnt lgkmcnt(0)" ::: "memory"); \
    __builtin_amdgcn_s_barrier(); \
    __builtin_amdgcn_sched_barrier(0); \
} while (0)

// ---------------------------------------------------------------------------
// bf16 MFMA GEMM: C(8192 x N) = A(8192 x K) @ B(N x K)^T + bias.
// BM=128, BN=64, BK=64, 256 thr = 4 waves.  (R12 configuration)
// ---------------------------------------------------------------------------
__global__ __launch_bounds__(256) void gemm_mfma(
    const float* __restrict__ A, int lda,
    const float* __restrict__ B, int ldb,
    const float* __restrict__ bias1, const float* __restrict__ bias2,
    float* __restrict__ C, int ldc,
    int N, int K,
    const int* __restrict__ gatherWords, int permGates)
{
    __shared__ unsigned int As_[2][4096];
    __shared__ unsigned int Bs_[2][2048];

    const int tid = threadIdx.x;
    const int row0 = blockIdx.x * 128;
    const int col0 = blockIdx.y * 64;
    const int lane = tid & 63;
    const int wave = tid >> 6;
    const int wr = wave >> 1, wc = wave & 1;
    const int nsteps = (K + 63) >> 6;

    const float* arow[8]; int aoff[8]; int kqA[8];
    #pragma unroll
    for (int j = 0; j < 8; ++j) {
        int v = tid + 256 * j;
        int row = v >> 4, kq = v & 15;
        int grow = row0 + row;
        const float* ap;
        if (gatherWords) {
            int widx = gatherWords[(grow & 31) * TT + (grow >> 5)];
            ap = A + (size_t)widx * lda;
        } else {
            ap = A + (size_t)grow * lda;
        }
        arow[j] = ap + 4 * kq;
        aoff[j] = (row >> 4) * 512 + (kq >> 3) * 256 + ((kq >> 1) & 3) * 64
                + (row & 15) * 4 + (kq & 1) * 2;
        kqA[j] = kq;
    }
    const float* brow[4]; int boff[4]; int bok[4]; int kqB[4];
    #pragma unroll
    for (int j = 0; j < 4; ++j) {
        int v = tid + 256 * j;
        int r = v >> 4, kq = v & 15;
        int gcol = col0 + r;
        bok[j] = (gcol < N);
        int src = bok[j] ? gcol : 0;
        if (permGates && bok[j]) {
            int d2 = (gcol >= 400) ? 1 : 0;
            int rr = gcol - d2 * 400;
            src = d2 * 400 + (rr & 3) * 100 + (rr >> 2);
        }
        brow[j] = B + (size_t)src * ldb + 4 * kq;
        boff[j] = (r >> 4) * 512 + (kq >> 3) * 256 + ((kq >> 1) & 3) * 64
                + (r & 15) * 4 + (kq & 1) * 2;
        kqB[j] = kq;
    }

    {
        #pragma unroll
        for (int j = 0; j < 8; ++j) {
            f32x4 v = {0.f,0.f,0.f,0.f};
            if (4 * kqA[j] < K) v = *(const f32x4*)(arow[j]);
            As_[0][aoff[j]]     = bfpack(v.x, v.y);
            As_[0][aoff[j] + 1] = bfpack(v.z, v.w);
        }
        #pragma unroll
        for (int j = 0; j < 4; ++j) {
            f32x4 v = {0.f,0.f,0.f,0.f};
            if (bok[j] && 4 * kqB[j] < K) v = *(const f32x4*)(brow[j]);
            Bs_[0][boff[j]]     = bfpack(v.x, v.y);
            Bs_[0][boff[j] + 1] = bfpack(v.z, v.w);
        }
    }
    BAR();

    f32x4 acc[4][2] = {};

    for (int s = 0; s < nsteps; ++s) {
        const int cur = s & 1, nxt = cur ^ 1;

        f32x4 la[8], lb[4];
        if (s + 1 < nsteps) {
            const int kb = (s + 1) * 64;
            #pragma unroll
            for (int j = 0; j < 8; ++j) {
                la[j] = (f32x4){0.f,0.f,0.f,0.f};
                if (kb + 4 * kqA[j] < K) la[j] = *(const f32x4*)(arow[j] + kb);
            }
            #pragma unroll
            for (int j = 0; j < 4; ++j) {
                lb[j] = (f32x4){0.f,0.f,0.f,0.f};
                if (bok[j] && kb + 4 * kqB[j] < K) lb[j] = *(const f32x4*)(brow[j] + kb);
            }
        }

        u32x4 af[2][4], bf2[2][2];
        #pragma unroll
        for (int f = 0; f < 2; ++f) {
            #pragma unroll
            for (int mt = 0; mt < 4; ++mt)
                af[f][mt] = *(const u32x4*)&As_[cur][(4 * wr + mt) * 512 + f * 256 + lane * 4];
            #pragma unroll
            for (int nt = 0; nt < 2; ++nt)
                bf2[f][nt] = *(const u32x4*)&Bs_[cur][(2 * wc + nt) * 512 + f * 256 + lane * 4];
        }
        #pragma unroll
        for (int f = 0; f < 2; ++f)
            #pragma unroll
            for (int mt = 0; mt < 4; ++mt)
                #pragma unroll
                for (int nt = 0; nt < 2; ++nt)
                    acc[mt][nt] = __builtin_amdgcn_mfma_f32_16x16x32_bf16(
                        asfrag(af[f][mt]), asfrag(bf2[f][nt]), acc[mt][nt], 0, 0, 0);

        if (s + 1 < nsteps) {
            #pragma unroll
            for (int j = 0; j < 8; ++j) {
                As_[nxt][aoff[j]]     = bfpack(la[j].x, la[j].y);
                As_[nxt][aoff[j] + 1] = bfpack(la[j].z, la[j].w);
            }
            #pragma unroll
            for (int j = 0; j < 4; ++j) {
                Bs_[nxt][boff[j]]     = bfpack(lb[j].x, lb[j].y);
                Bs_[nxt][boff[j] + 1] = bfpack(lb[j].z, lb[j].w);
            }
        }
        BAR();
    }

    const int r4 = (lane >> 4) * 4;
    const int cl = lane & 15;
    #pragma unroll
    for (int nt = 0; nt < 2; ++nt) {
        int gcol = col0 + (2 * wc + nt) * 16 + cl;
        if (gcol < N) {
            int src = gcol;
            if (permGates) {
                int d2 = (gcol >= 400) ? 1 : 0;
                int rr = gcol - d2 * 400;
                src = d2 * 400 + (rr & 3) * 100 + (rr >> 2);
            }
            float bv = bias1[src];
            if (bias2) bv += bias2[src];
            #pragma unroll
            for (int mt = 0; mt < 4; ++mt) {
                int grow = row0 + (4 * wr + mt) * 16 + r4;
                #pragma unroll
                for (int r = 0; r < 4; ++r)
                    C[(size_t)(grow + r) * ldc + gcol] = acc[mt][nt][r] + bv;
            }
        }
    }
}

// ---------------------------------------------------------------------------
// MFMA LSTM recurrence -- R18: BOTH DIRECTIONS FUSED IN ONE BLOCK.
// R12 core (measured 173 us) ran 1 wave/SIMD: every instruction exposed --
// step 1620 cyc vs ~450 theoretical latency chain.  m114-verified fix: TLP
// from an INDEPENDENT co-resident wave.  The fwd/bwd directions are fully
// independent chains; fusing them gives 2 waves/SIMD with independent
// streams.  Grid 32 (one block per batch), 512 thr = 8 waves: waves 0-3 =
// dir0, waves 4-7 = dir1 (each group = exact R12 structure).  Shared
// barrier locksteps the dirs (same work shape -- harmless).  Chunk 16->8
// steps so LDS fits: preS 2dir x 2buf x 8x400 f32 = 51.2 KB (+1 KB h16).
// Regs: 136 VGPR + 112 AGPR = 248 <= 256 -> exactly 2 waves/SIMD.
// ---------------------------------------------------------------------------
#define STASH_FRAG(SS, F, A0,A1,A2,A3) { \
    int tile = base + (SS); if (tile > 24) tile = 24; \
    int row16 = 16*tile + m16; \
    const float* srcp = Whh + (size_t)(dir*400 + (row16 & 3)*100 + (row16 >> 2)) * HID; \
    const int k0 = 32*(F) + 8*g4; \
    f32x4 fa = {0.f,0.f,0.f,0.f}, fb = {0.f,0.f,0.f,0.f}; \
    if (k0 < HID) fa = *(const f32x4*)(srcp + k0); \
    if (k0 + 4 < HID) fb = *(const f32x4*)(srcp + k0 + 4); \
    unsigned p0 = bfpack(fa.x, fa.y), p1 = bfpack(fa.z, fa.w); \
    unsigned p2 = bfpack(fb.x, fb.y), p3 = bfpack(fb.z, fb.w); \
    asm volatile("v_accvgpr_write_b32 a" #A0 ", %0\n\t" \
                 "v_accvgpr_write_b32 a" #A1 ", %1\n\t" \
                 "v_accvgpr_write_b32 a" #A2 ", %2\n\t" \
                 "v_accvgpr_write_b32 a" #A3 ", %3" \
                 :: "v"(p0), "v"(p1), "v"(p2), "v"(p3) \
                 : "a" #A0, "a" #A1, "a" #A2, "a" #A3); }

#define MF(ACC, BF, A0, A3) \
    asm volatile("v_mfma_f32_16x16x32_bf16 %0, a[" #A0 ":" #A3 "], %1, %0" \
                 : "+v"(ACC) : "v"(BF));

// chunk = 8 steps x 400 gates = 800 f32x4 per dir; staged by the dir's own
// 256 threads (4 slots each, masked).
#define LOADCHUNK(K2) { \
    const int s0_ = 8 * (K2); \
    _Pragma("unroll") \
    for (int j = 0; j < 4; ++j) { \
        if (okj[j]) { \
            int tg = dir ? (TT - 1 - (s0_ + sicj[j])) : (s0_ + sicj[j]); \
            rr[j] = *(const f32x4*)(pre + (size_t)(tg * BB + b) * 800 + dir * 400 + 4 * gqj[j]); \
        } \
    } }

#define WRITECHUNK(BUF) { \
    _Pragma("unroll") \
    for (int j = 0; j < 4; ++j) { \
        if (okj[j]) *(f32x4*)&preS[dir][(BUF) * 3200 + sicj[j] * 400 + 4 * gqj[j]] = rr[j]; \
    } }

#define LSTM_STEP(SIC) { \
    const int t_ = dir ? (TT - 1 - (s0 + (SIC))) : (s0 + (SIC)); \
    const int i_ = t_ * BB + b; \
    const u32x4* hb_ = (const u32x4*)&h16[dir][(SIC) & 1][0]; \
    u32x4 bf0 = hb_[g4], bf1 = hb_[4+g4], bf2 = hb_[8+g4], bf3 = hb_[12+g4]; \
    f32x4 p4 = *(const f32x4*)&preS[dir][curbase + (SIC) * 400 + my_po]; \
    f32x4 acc0 = {0.f,0.f,0.f,0.f}, acc1 = {0.f,0.f,0.f,0.f}; \
    f32x4 acc2 = {0.f,0.f,0.f,0.f}, acc3 = {0.f,0.f,0.f,0.f}; \
    f32x4 acc4 = {0.f,0.f,0.f,0.f}, acc5 = {0.f,0.f,0.f,0.f}; \
    f32x4 acc6 = {0.f,0.f,0.f,0.f}; \
    asm volatile("s_nop 1"); \
    MF(acc0, bf0, 0, 3)    MF(acc1, bf0, 16, 19)  MF(acc2, bf0, 32, 35) \
    MF(acc3, bf0, 48, 51)  MF(acc4, bf0, 64, 67)  MF(acc5, bf0, 80, 83) \
    MF(acc6, bf0, 96, 99) \
    MF(acc0, bf1, 4, 7)    MF(acc1, bf1, 20, 23)  MF(acc2, bf1, 36, 39) \
    MF(acc3, bf1, 52, 55)  MF(acc4, bf1, 68, 71)  MF(acc5, bf1, 84, 87) \
    MF(acc6, bf1, 100, 103) \
    MF(acc0, bf2, 8, 11)   MF(acc1, bf2, 24, 27)  MF(acc2, bf2, 40, 43) \
    MF(acc3, bf2, 56, 59)  MF(acc4, bf2, 72, 75)  MF(acc5, bf2, 88, 91) \
    MF(acc6, bf2, 104, 107) \
    MF(acc0, bf3, 12, 15)  MF(acc1, bf3, 28, 31)  MF(acc2, bf3, 44, 47) \
    MF(acc3, bf3, 60, 63)  MF(acc4, bf3, 76, 79)  MF(acc5, bf3, 92, 95) \
    MF(acc6, bf3, 108, 111) \
    asm volatile("s_nop 7\n\ts_nop 7"); \
    f32x4 t01 = (slot_sel & 1) ? acc1 : acc0; \
    f32x4 t23 = (slot_sel & 1) ? acc3 : acc2; \
    f32x4 t45 = (slot_sel & 1) ? acc5 : acc4; \
    f32x4 u0 = (slot_sel & 2) ? t23 : t01; \
    f32x4 u1 = (slot_sel & 2) ? acc6 : t45; \
    f32x4 sel = (slot_sel & 4) ? u1 : u0; \
    float igt = sigm(sel.x + p4.x); \
    float fgt = sigm(sel.y + p4.y); \
    float ggt = tanh_(sel.z + p4.z); \
    float ogt = sigm(sel.w + p4.w); \
    c = fgt * c + igt * ggt; \
    float h = ogt * tanh_(c); \
    if (writer) { \
        h16[dir][((SIC) + 1) & 1][my_u] = (unsigned short)bfr(h); \
        hout[(size_t)i_ * 200 + dir * HID + my_u] = h; \
    } \
    BAR(); }

__global__ __launch_bounds__(512, 1) void lstm_mfma(
    const float* __restrict__ pre,
    const float* __restrict__ Whh,
    float* __restrict__ hout)
{
    const int b = blockIdx.x;           // batch 0..31
    const int tid = threadIdx.x;
    const int wave = tid >> 6;          // 0..7
    const int dir = wave >> 2;          // waves 0-3: dir0, waves 4-7: dir1
    const int wavel = wave & 3;         // wave within direction group
    const int lane = tid & 63;
    const int m16 = lane & 15;
    const int g4 = lane >> 4;           // k-octet group / unit-in-tile
    const int slot_sel = lane & 7;      // epilogue tile-slot
    const int tidl = tid & 255;         // thread within direction group

    const int base = (wavel == 0) ? 0 : (wavel == 1) ? 7 : (wavel == 2) ? 13 : 19;

    __shared__ alignas(16) unsigned short h16[2][2][128];   // [dir][buf][unit]
    __shared__ alignas(16) float preS[2][6400];  // [dir][buf*3200 + sic*400 + gate]

    STASH_FRAG(0,0, 0,1,2,3)      STASH_FRAG(0,1, 4,5,6,7)
    STASH_FRAG(0,2, 8,9,10,11)    STASH_FRAG(0,3, 12,13,14,15)
    STASH_FRAG(1,0, 16,17,18,19)  STASH_FRAG(1,1, 20,21,22,23)
    STASH_FRAG(1,2, 24,25,26,27)  STASH_FRAG(1,3, 28,29,30,31)
    STASH_FRAG(2,0, 32,33,34,35)  STASH_FRAG(2,1, 36,37,38,39)
    STASH_FRAG(2,2, 40,41,42,43)  STASH_FRAG(2,3, 44,45,46,47)
    STASH_FRAG(3,0, 48,49,50,51)  STASH_FRAG(3,1, 52,53,54,55)
    STASH_FRAG(3,2, 56,57,58,59)  STASH_FRAG(3,3, 60,61,62,63)
    STASH_FRAG(4,0, 64,65,66,67)  STASH_FRAG(4,1, 68,69,70,71)
    STASH_FRAG(4,2, 72,73,74,75)  STASH_FRAG(4,3, 76,77,78,79)
    STASH_FRAG(5,0, 80,81,82,83)  STASH_FRAG(5,1, 84,85,86,87)
    STASH_FRAG(5,2, 88,89,90,91)  STASH_FRAG(5,3, 92,93,94,95)
    STASH_FRAG(6,0, 96,97,98,99)  STASH_FRAG(6,1, 100,101,102,103)
    STASH_FRAG(6,2, 104,105,106,107) STASH_FRAG(6,3, 108,109,110,111)

    if (tid < 512) {
        unsigned short* hz = (unsigned short*)h16;
        if (tid < 2 * 2 * 128) hz[tid] = 0;
    }

    int my_tile = base + ((slot_sel < 7) ? slot_sel : 6);
    if (my_tile > 24) my_tile = 24;
    const int my_u = 4 * my_tile + g4;                 // 0..99
    const int my_po = 16 * my_tile + 4 * g4;           // pre offset (floats)
    const int ow_lim = (wavel == 0) ? 7 : 6;
    const bool writer = (slot_sel < ow_lim) && ((lane & 8) == 0);

    // chunk staging: 800 f32x4 per dir over 256 threads -> 4 masked slots
    int sicj[4], gqj[4]; bool okj[4];
    #pragma unroll
    for (int j = 0; j < 4; ++j) {
        int idx = tidl + 256 * j;
        okj[j] = (idx < 800);
        int ic = okj[j] ? idx : 0;
        sicj[j] = ic / 100;
        gqj[j] = ic - 100 * sicj[j];
    }

    float c = 0.f;
    f32x4 rr[4];

    LOADCHUNK(0)
    WRITECHUNK(0)
    LOADCHUNK(1)
    BAR();

    for (int k = 0; k < 32; ++k) {
        const int s0 = 8 * k;
        const int curbase = (k & 1) * 3200;
        LSTM_STEP(0)  LSTM_STEP(1)  LSTM_STEP(2)  LSTM_STEP(3)
        LSTM_STEP(4)  LSTM_STEP(5)  LSTM_STEP(6)  LSTM_STEP(7)
        if (k < 31) { WRITECHUNK((k & 1) ^ 1) }
        if (k < 30) { LOADCHUNK(k + 2) }
        BAR();
    }
}

// ---------------------------------------------------------------------------
// logits + log_softmax: one 32-lane half-wave per token.
// ---------------------------------------------------------------------------
__global__ __launch_bounds__(256) void logits_lsm(
    const float* __restrict__ h1,
    const float* __restrict__ out_w,
    const float* __restrict__ out_b,
    float* __restrict__ logits)
{
    const int lane = threadIdx.x & 63;
    const int wid = (blockIdx.x * 256 + threadIdx.x) >> 6;
    const int half = lane >> 5;
    const int n = lane & 31;
    const int i = wid * 2 + half;
    if (i >= NTOK) return;

    float acc = -1e30f;
    if (n < NTAGS) {
        acc = out_b[n];
        const float4* hr = (const float4*)(h1 + (size_t)i * 200);
        const float4* wr = (const float4*)(out_w + (size_t)n * 200);
        #pragma unroll
        for (int e = 0; e < 50; ++e) {
            float4 h4 = hr[e], w4 = wr[e];
            acc += h4.x * w4.x + h4.y * w4.y + h4.z * w4.z + h4.w * w4.w;
        }
    }
    float m = acc;
    for (int off = 16; off > 0; off >>= 1) m = fmaxf(m, __shfl_xor(m, off, 32));
    float ex = (n < NTAGS) ? __expf(acc - m) : 0.f;
    float s = ex;
    for (int off = 16; off > 0; off >>= 1) s += __shfl_xor(s, off, 32);
    if (n < NTAGS) logits[(size_t)i * NTAGS + n] = acc - m - __logf(s);
}

// ---------------------------------------------------------------------------
// CRF loss: one wave per batch element (R11 version).
// ---------------------------------------------------------------------------
__global__ __launch_bounds__(64) void crf_kernel(
    const float* __restrict__ logits,
    const int* __restrict__ words,
    const int* __restrict__ target,
    const float* __restrict__ trans,
    const float* __restrict__ start_s,
    const float* __restrict__ end_s,
    float* __restrict__ out)
{
    const int b = blockIdx.x;
    const int j = threadIdx.x;
    const int j21 = (j < NTAGS) ? j : (NTAGS - 1);

    float tcol[NTAGS];
    #pragma unroll
    for (int i = 0; i < NTAGS; ++i) tcol[i] = (j < NTAGS) ? trans[i * NTAGS + j] : 0.f;

    const int w0 = words[b * TT +   0 + j];
    const int w1 = words[b * TT +  64 + j];
    const int w2 = words[b * TT + 128 + j];
    const int w3 = words[b * TT + 192 + j];

    float alpha = (j < NTAGS) ? (logits[(size_t)(0 * BB + b) * NTAGS + j] + start_s[j]) : -1e30f;
    float e_cur = logits[(size_t)(1 * BB + b) * NTAGS + j21];

#define CRF_CHUNK(WREG, T0) \
    for (int u = ((T0) == 0 ? 1 : 0); u < 64; ++u) { \
        const int t = (T0) + u; \
        float e_nxt = 0.f; \
        if (t + 1 < TT) e_nxt = logits[(size_t)((t + 1) * BB + b) * NTAGS + j21]; \
        if (__shfl(WREG, u, 64) != 0) { \
            float v[NTAGS]; \
            _Pragma("unroll") \
            for (int i2 = 0; i2 < NTAGS; ++i2) \
                v[i2] = __shfl(alpha, i2, 64) + tcol[i2]; \
            float m0[11]; \
            _Pragma("unroll") \
            for (int p = 0; p < 10; ++p) m0[p] = fmaxf(v[2*p], v[2*p+1]); \
            m0[10] = v[20]; \
            float m1[6]; \
            _Pragma("unroll") \
            for (int p = 0; p < 5; ++p) m1[p] = fmaxf(m0[2*p], m0[2*p+1]); \
            m1[5] = m0[10]; \
            float m2a = fmaxf(m1[0], m1[1]), m2b = fmaxf(m1[2], m1[3]), m2c = fmaxf(m1[4], m1[5]); \
            float mx = fmaxf(fmaxf(m2a, m2b), m2c); \
            float e[NTAGS]; \
            _Pragma("unroll") \
            for (int i2 = 0; i2 < NTAGS; ++i2) e[i2] = __expf(v[i2] - mx); \
            float s0[11]; \
            _Pragma("unroll") \
            for (int p = 0; p < 10; ++p) s0[p] = e[2*p] + e[2*p+1]; \
            s0[10] = e[20]; \
            float s1[6]; \
            _Pragma("unroll") \
            for (int p = 0; p < 5; ++p) s1[p] = s0[2*p] + s0[2*p+1]; \
            s1[5] = s0[10]; \
            float ss = ((s1[0] + s1[1]) + (s1[2] + s1[3])) + (s1[4] + s1[5]); \
            float na = mx + __logf(ss) + e_cur; \
            alpha = (j < NTAGS) ? na : -1e30f; \
        } \
        e_cur = e_nxt; \
    }

    CRF_CHUNK(w0, 0)
    CRF_CHUNK(w1, 64)
    CRF_CHUNK(w2, 128)
    CRF_CHUNK(w3, 192)
#undef CRF_CHUNK

    float val = (j < NTAGS) ? (alpha + end_s[j]) : -1e30f;
    float mx = val;
    for (int off = 32; off > 0; off >>= 1) mx = fmaxf(mx, __shfl_xor(mx, off, 64));
    float s = (j < NTAGS) ? __expf(val - mx) : 0.f;
    for (int off = 32; off > 0; off >>= 1) s += __shfl_xor(s, off, 64);
    float norm = mx + __logf(s);

    float gold = 0.f, slen = 0.f;
    for (int t = j; t < TT; t += 64) {
        int tg = target[b * TT + t];
        bool m = (words[b * TT + t] != 0);
        if (m) {
            gold += logits[(size_t)(t * BB + b) * NTAGS + tg];
            slen += 1.f;
            if (t >= 1) gold += trans[target[b * TT + t - 1] * NTAGS + tg];
        }
    }
    for (int off = 32; off > 0; off >>= 1) {
        gold += __shfl_xor(gold, off, 64);
        slen += __shfl_xor(slen, off, 64);
    }
    if (j == 0) {
        int len = (int)slen;
        int last = (len > 0) ? (len - 1) : 0;
        int last_tag = target[b * TT + last];
        gold += start_s[target[b * TT + 0]] + end_s[last_tag];
        out[b] = norm - gold;
    }
}

// ---------------------------------------------------------------------------
extern "C" void kernel_launch(void* const* d_in, const int* in_sizes, int n_in,
                              void* d_out, int out_size, void* d_ws, size_t ws_size,
                              hipStream_t stream) {
    const int*   words   = (const int*)  d_in[0];
    const int*   target  = (const int*)  d_in[1];
    const float* embed   = (const float*)d_in[2];
    const float* in_fc_w = (const float*)d_in[3];
    const float* in_fc_b = (const float*)d_in[4];
    const float* Wih0    = (const float*)d_in[5];
    const float* Whh0    = (const float*)d_in[6];
    const float* bih0    = (const float*)d_in[7];
    const float* bhh0    = (const float*)d_in[8];
    const float* Wih1    = (const float*)d_in[9];
    const float* Whh1    = (const float*)d_in[10];
    const float* bih1    = (const float*)d_in[11];
    const float* bhh1    = (const float*)d_in[12];
    const float* out_w   = (const float*)d_in[13];
    const float* out_b   = (const float*)d_in[14];
    const float* trans   = (const float*)d_in[15];
    const float* start_s = (const float*)d_in[16];
    const float* end_s   = (const float*)d_in[17];
    float* out = (float*)d_out;

    float* ws = (float*)d_ws;
    // layout (floats): x [0,2097152)  pre [2097152,8650752)  h0 [8650752,10289152)
    //                  h1 = x region  logits [1638400,1810432)
    float* x      = ws;
    float* pre    = ws + 2097152;
    float* h0     = ws + 8650752;
    float* h1     = ws;
    float* logits = ws + 1638400;

    // 1) x = gather(embed, words) @ in_fc_w^T + in_fc_b     (8192 x 256)
    gemm_mfma<<<dim3(64, 4), 256, 0, stream>>>(
        embed, EMBED, in_fc_w, EMBED, in_fc_b, nullptr,
        x, DMODEL, DMODEL, EMBED, words, 0);

    // 2) pre0 = x @ Wih0^T (gate-permuted) + (bih0 + bhh0)  (8192 x 800)
    gemm_mfma<<<dim3(64, 13), 256, 0, stream>>>(
        x, DMODEL, Wih0, DMODEL, bih0, bhh0,
        pre, 800, 800, DMODEL, nullptr, 1);

    // 3) layer0 recurrence -> h0 (8192 x 200)   [fused dirs: 32 x 512]
    lstm_mfma<<<32, 512, 0, stream>>>(pre, Whh0, h0);

    // 4) pre1 = h0 @ Wih1^T (gate-permuted) + (bih1 + bhh1) (8192 x 800)
    gemm_mfma<<<dim3(64, 13), 256, 0, stream>>>(
        h0, 200, Wih1, 200, bih1, bhh1,
        pre, 800, 800, 200, nullptr, 1);

    // 5) layer1 recurrence -> h1 (8192 x 200)   [fused dirs: 32 x 512]
    lstm_mfma<<<32, 512, 0, stream>>>(pre, Whh1, h1);

    // 6) logits + log_softmax (8192 x 21)
    logits_lsm<<<NTOK / 8, 256, 0, stream>>>(h1, out_w, out_b, logits);

    // 7) CRF loss -> out (32)
    crf_kernel<<<BB, 64, 0, stream>>>(logits, words, target, trans, start_s, end_s, out);
}

// Round 19
// 559.062 us; speedup vs baseline: 1.2760x; 1.2760x over previous
//
#include <hip/hip_runtime.h>
#include <hip/hip_bf16.h>

// Model dims
#define VOCAB 21128
#define EMBED 768
#define DMODEL 256
#define HID 100
#define NTAGS 21
#define BB 32
#define TT 256
#define NTOK (BB*TT)   // 8192 tokens, token index i = t*BB + b

typedef float f32x4 __attribute__((ext_vector_type(4)));
typedef unsigned int u32x4 __attribute__((ext_vector_type(4)));
typedef short s16x8 __attribute__((ext_vector_type(8)));

__device__ __forceinline__ float sigm(float x) { return 1.0f / (1.0f + __expf(-x)); }
__device__ __forceinline__ float tanh_(float x) { return 2.0f / (1.0f + __expf(-2.0f * x)) - 1.0f; }

__device__ __forceinline__ unsigned int bfr(float x) {
    unsigned int u = __float_as_uint(x);
    return (u + 0x7fffu + ((u >> 16) & 1u)) >> 16;
}
__device__ __forceinline__ unsigned int bfpack(float lo, float hi) {
    return (bfr(hi) << 16) | bfr(lo);
}
__device__ __forceinline__ s16x8 asfrag(u32x4 v) {
    union { u32x4 u; s16x8 s; } x; x.u = v; return x.s;
}

// Raw barrier: fence LDS only; vmem rides across.
#define BAR() do { \
    asm volatile("s_waitcnt lgkmcnt(0)" ::: "memory"); \
    __builtin_amdgcn_s_barrier(); \
    __builtin_amdgcn_sched_barrier(0); \
} while (0)

// ---------------------------------------------------------------------------
// bf16 MFMA GEMM: C(8192 x N) = A(8192 x K) @ B(N x K)^T + bias.
// BM=128, BN=64, BK=64, 256 thr = 4 waves.  (R12 configuration)
// ---------------------------------------------------------------------------
__global__ __launch_bounds__(256) void gemm_mfma(
    const float* __restrict__ A, int lda,
    const float* __restrict__ B, int ldb,
    const float* __restrict__ bias1, const float* __restrict__ bias2,
    float* __restrict__ C, int ldc,
    int N, int K,
    const int* __restrict__ gatherWords, int permGates)
{
    __shared__ unsigned int As_[2][4096];
    __shared__ unsigned int Bs_[2][2048];

    const int tid = threadIdx.x;
    const int row0 = blockIdx.x * 128;
    const int col0 = blockIdx.y * 64;
    const int lane = tid & 63;
    const int wave = tid >> 6;
    const int wr = wave >> 1, wc = wave & 1;
    const int nsteps = (K + 63) >> 6;

    const float* arow[8]; int aoff[8]; int kqA[8];
    #pragma unroll
    for (int j = 0; j < 8; ++j) {
        int v = tid + 256 * j;
        int row = v >> 4, kq = v & 15;
        int grow = row0 + row;
        const float* ap;
        if (gatherWords) {
            int widx = gatherWords[(grow & 31) * TT + (grow >> 5)];
            ap = A + (size_t)widx * lda;
        } else {
            ap = A + (size_t)grow * lda;
        }
        arow[j] = ap + 4 * kq;
        aoff[j] = (row >> 4) * 512 + (kq >> 3) * 256 + ((kq >> 1) & 3) * 64
                + (row & 15) * 4 + (kq & 1) * 2;
        kqA[j] = kq;
    }
    const float* brow[4]; int boff[4]; int bok[4]; int kqB[4];
    #pragma unroll
    for (int j = 0; j < 4; ++j) {
        int v = tid + 256 * j;
        int r = v >> 4, kq = v & 15;
        int gcol = col0 + r;
        bok[j] = (gcol < N);
        int src = bok[j] ? gcol : 0;
        if (permGates && bok[j]) {
            int d2 = (gcol >= 400) ? 1 : 0;
            int rr = gcol - d2 * 400;
            src = d2 * 400 + (rr & 3) * 100 + (rr >> 2);
        }
        brow[j] = B + (size_t)src * ldb + 4 * kq;
        boff[j] = (r >> 4) * 512 + (kq >> 3) * 256 + ((kq >> 1) & 3) * 64
                + (r & 15) * 4 + (kq & 1) * 2;
        kqB[j] = kq;
    }

    {
        #pragma unroll
        for (int j = 0; j < 8; ++j) {
            f32x4 v = {0.f,0.f,0.f,0.f};
            if (4 * kqA[j] < K) v = *(const f32x4*)(arow[j]);
            As_[0][aoff[j]]     = bfpack(v.x, v.y);
            As_[0][aoff[j] + 1] = bfpack(v.z, v.w);
        }
        #pragma unroll
        for (int j = 0; j < 4; ++j) {
            f32x4 v = {0.f,0.f,0.f,0.f};
            if (bok[j] && 4 * kqB[j] < K) v = *(const f32x4*)(brow[j]);
            Bs_[0][boff[j]]     = bfpack(v.x, v.y);
            Bs_[0][boff[j] + 1] = bfpack(v.z, v.w);
        }
    }
    BAR();

    f32x4 acc[4][2] = {};

    for (int s = 0; s < nsteps; ++s) {
        const int cur = s & 1, nxt = cur ^ 1;

        f32x4 la[8], lb[4];
        if (s + 1 < nsteps) {
            const int kb = (s + 1) * 64;
            #pragma unroll
            for (int j = 0; j < 8; ++j) {
                la[j] = (f32x4){0.f,0.f,0.f,0.f};
                if (kb + 4 * kqA[j] < K) la[j] = *(const f32x4*)(arow[j] + kb);
            }
            #pragma unroll
            for (int j = 0; j < 4; ++j) {
                lb[j] = (f32x4){0.f,0.f,0.f,0.f};
                if (bok[j] && kb + 4 * kqB[j] < K) lb[j] = *(const f32x4*)(brow[j] + kb);
            }
        }

        u32x4 af[2][4], bf2[2][2];
        #pragma unroll
        for (int f = 0; f < 2; ++f) {
            #pragma unroll
            for (int mt = 0; mt < 4; ++mt)
                af[f][mt] = *(const u32x4*)&As_[cur][(4 * wr + mt) * 512 + f * 256 + lane * 4];
            #pragma unroll
            for (int nt = 0; nt < 2; ++nt)
                bf2[f][nt] = *(const u32x4*)&Bs_[cur][(2 * wc + nt) * 512 + f * 256 + lane * 4];
        }
        #pragma unroll
        for (int f = 0; f < 2; ++f)
            #pragma unroll
            for (int mt = 0; mt < 4; ++mt)
                #pragma unroll
                for (int nt = 0; nt < 2; ++nt)
                    acc[mt][nt] = __builtin_amdgcn_mfma_f32_16x16x32_bf16(
                        asfrag(af[f][mt]), asfrag(bf2[f][nt]), acc[mt][nt], 0, 0, 0);

        if (s + 1 < nsteps) {
            #pragma unroll
            for (int j = 0; j < 8; ++j) {
                As_[nxt][aoff[j]]     = bfpack(la[j].x, la[j].y);
                As_[nxt][aoff[j] + 1] = bfpack(la[j].z, la[j].w);
            }
            #pragma unroll
            for (int j = 0; j < 4; ++j) {
                Bs_[nxt][boff[j]]     = bfpack(lb[j].x, lb[j].y);
                Bs_[nxt][boff[j] + 1] = bfpack(lb[j].z, lb[j].w);
            }
        }
        BAR();
    }

    const int r4 = (lane >> 4) * 4;
    const int cl = lane & 15;
    #pragma unroll
    for (int nt = 0; nt < 2; ++nt) {
        int gcol = col0 + (2 * wc + nt) * 16 + cl;
        if (gcol < N) {
            int src = gcol;
            if (permGates) {
                int d2 = (gcol >= 400) ? 1 : 0;
                int rr = gcol - d2 * 400;
                src = d2 * 400 + (rr & 3) * 100 + (rr >> 2);
            }
            float bv = bias1[src];
            if (bias2) bv += bias2[src];
            #pragma unroll
            for (int mt = 0; mt < 4; ++mt) {
                int grow = row0 + (4 * wr + mt) * 16 + r4;
                #pragma unroll
                for (int r = 0; r < 4; ++r)
                    C[(size_t)(grow + r) * ldc + gcol] = acc[mt][nt][r] + bv;
            }
        }
    }
}

// ---------------------------------------------------------------------------
// MFMA LSTM recurrence -- R12 configuration (measured best: 173 us; session
// optimum reproduced twice at 560 us total).  64 blocks = (dir<<5)|b,
// 4 waves x 7 tile-slots, weights in 112 physical AGPRs, preS b128 chunk
// staging (16 steps, double-buffered), lgkm-only barriers.
// Falsified alternatives: deeper prefetch (R8), 2-phase epilogue (R10),
// sched_barrier A/B (R11 null), conflict-free preS (R13 slower), hout
// buffering (R14 neutral), batch-in-N (R15/R16: HBM-concurrency-bound at
// 4 blocks), dir-fusion (R18: barrier couples dirs, 40% overlap only).
// ---------------------------------------------------------------------------
#define STASH_FRAG(SS, F, A0,A1,A2,A3) { \
    int tile = base + (SS); if (tile > 24) tile = 24; \
    int row16 = 16*tile + m16; \
    const float* srcp = Whh + (size_t)(dir*400 + (row16 & 3)*100 + (row16 >> 2)) * HID; \
    const int k0 = 32*(F) + 8*g4; \
    f32x4 fa = {0.f,0.f,0.f,0.f}, fb = {0.f,0.f,0.f,0.f}; \
    if (k0 < HID) fa = *(const f32x4*)(srcp + k0); \
    if (k0 + 4 < HID) fb = *(const f32x4*)(srcp + k0 + 4); \
    unsigned p0 = bfpack(fa.x, fa.y), p1 = bfpack(fa.z, fa.w); \
    unsigned p2 = bfpack(fb.x, fb.y), p3 = bfpack(fb.z, fb.w); \
    asm volatile("v_accvgpr_write_b32 a" #A0 ", %0\n\t" \
                 "v_accvgpr_write_b32 a" #A1 ", %1\n\t" \
                 "v_accvgpr_write_b32 a" #A2 ", %2\n\t" \
                 "v_accvgpr_write_b32 a" #A3 ", %3" \
                 :: "v"(p0), "v"(p1), "v"(p2), "v"(p3) \
                 : "a" #A0, "a" #A1, "a" #A2, "a" #A3); }

#define MF(ACC, BF, A0, A3) \
    asm volatile("v_mfma_f32_16x16x32_bf16 %0, a[" #A0 ":" #A3 "], %1, %0" \
                 : "+v"(ACC) : "v"(BF));

#define LOADCHUNK(K2) { \
    const int s0_ = 16 * (K2); \
    _Pragma("unroll") \
    for (int j = 0; j < 7; ++j) { \
        if (okj[j]) { \
            int tg = dir ? (TT - 1 - (s0_ + sicj[j])) : (s0_ + sicj[j]); \
            rr[j] = *(const f32x4*)(pre + (size_t)(tg * BB + b) * 800 + dir * 400 + 4 * gqj[j]); \
        } \
    } }

#define WRITECHUNK(BUF) { \
    _Pragma("unroll") \
    for (int j = 0; j < 7; ++j) { \
        if (okj[j]) *(f32x4*)&preS[(BUF) * 6400 + sicj[j] * 400 + 4 * gqj[j]] = rr[j]; \
    } }

#define LSTM_STEP(SIC) { \
    const int t_ = dir ? (TT - 1 - (s0 + (SIC))) : (s0 + (SIC)); \
    const int i_ = t_ * BB + b; \
    const u32x4* hb_ = (const u32x4*)&h16[(SIC) & 1][0]; \
    u32x4 bf0 = hb_[g4], bf1 = hb_[4+g4], bf2 = hb_[8+g4], bf3 = hb_[12+g4]; \
    f32x4 p4 = *(const f32x4*)&preS[curbase + (SIC) * 400 + my_po]; \
    f32x4 acc0 = {0.f,0.f,0.f,0.f}, acc1 = {0.f,0.f,0.f,0.f}; \
    f32x4 acc2 = {0.f,0.f,0.f,0.f}, acc3 = {0.f,0.f,0.f,0.f}; \
    f32x4 acc4 = {0.f,0.f,0.f,0.f}, acc5 = {0.f,0.f,0.f,0.f}; \
    f32x4 acc6 = {0.f,0.f,0.f,0.f}; \
    asm volatile("s_nop 1"); \
    MF(acc0, bf0, 0, 3)    MF(acc1, bf0, 16, 19)  MF(acc2, bf0, 32, 35) \
    MF(acc3, bf0, 48, 51)  MF(acc4, bf0, 64, 67)  MF(acc5, bf0, 80, 83) \
    MF(acc6, bf0, 96, 99) \
    MF(acc0, bf1, 4, 7)    MF(acc1, bf1, 20, 23)  MF(acc2, bf1, 36, 39) \
    MF(acc3, bf1, 52, 55)  MF(acc4, bf1, 68, 71)  MF(acc5, bf1, 84, 87) \
    MF(acc6, bf1, 100, 103) \
    MF(acc0, bf2, 8, 11)   MF(acc1, bf2, 24, 27)  MF(acc2, bf2, 40, 43) \
    MF(acc3, bf2, 56, 59)  MF(acc4, bf2, 72, 75)  MF(acc5, bf2, 88, 91) \
    MF(acc6, bf2, 104, 107) \
    MF(acc0, bf3, 12, 15)  MF(acc1, bf3, 28, 31)  MF(acc2, bf3, 44, 47) \
    MF(acc3, bf3, 60, 63)  MF(acc4, bf3, 76, 79)  MF(acc5, bf3, 92, 95) \
    MF(acc6, bf3, 108, 111) \
    asm volatile("s_nop 7\n\ts_nop 7"); \
    f32x4 t01 = (slot_sel & 1) ? acc1 : acc0; \
    f32x4 t23 = (slot_sel & 1) ? acc3 : acc2; \
    f32x4 t45 = (slot_sel & 1) ? acc5 : acc4; \
    f32x4 u0 = (slot_sel & 2) ? t23 : t01; \
    f32x4 u1 = (slot_sel & 2) ? acc6 : t45; \
    f32x4 sel = (slot_sel & 4) ? u1 : u0; \
    float igt = sigm(sel.x + p4.x); \
    float fgt = sigm(sel.y + p4.y); \
    float ggt = tanh_(sel.z + p4.z); \
    float ogt = sigm(sel.w + p4.w); \
    c = fgt * c + igt * ggt; \
    float h = ogt * tanh_(c); \
    if (writer) { \
        h16[((SIC) + 1) & 1][my_u] = (unsigned short)bfr(h); \
        hout[(size_t)i_ * 200 + dir * HID + my_u] = h; \
    } \
    BAR(); }

__global__ __launch_bounds__(256, 1) void lstm_mfma(
    const float* __restrict__ pre,
    const float* __restrict__ Whh,
    float* __restrict__ hout)
{
    const int dir = blockIdx.x >> 5;
    const int b = blockIdx.x & 31;
    const int tid = threadIdx.x;
    const int wave = tid >> 6;          // 0..3
    const int lane = tid & 63;
    const int m16 = lane & 15;
    const int g4 = lane >> 4;           // k-octet group / unit-in-tile
    const int slot_sel = lane & 7;      // epilogue tile-slot

    const int base = (wave == 0) ? 0 : (wave == 1) ? 7 : (wave == 2) ? 13 : 19;

    __shared__ alignas(16) unsigned short h16[2][128];
    __shared__ alignas(16) float preS[2 * 6400];   // 2 x 16 steps x 400 gates

    STASH_FRAG(0,0, 0,1,2,3)      STASH_FRAG(0,1, 4,5,6,7)
    STASH_FRAG(0,2, 8,9,10,11)    STASH_FRAG(0,3, 12,13,14,15)
    STASH_FRAG(1,0, 16,17,18,19)  STASH_FRAG(1,1, 20,21,22,23)
    STASH_FRAG(1,2, 24,25,26,27)  STASH_FRAG(1,3, 28,29,30,31)
    STASH_FRAG(2,0, 32,33,34,35)  STASH_FRAG(2,1, 36,37,38,39)
    STASH_FRAG(2,2, 40,41,42,43)  STASH_FRAG(2,3, 44,45,46,47)
    STASH_FRAG(3,0, 48,49,50,51)  STASH_FRAG(3,1, 52,53,54,55)
    STASH_FRAG(3,2, 56,57,58,59)  STASH_FRAG(3,3, 60,61,62,63)
    STASH_FRAG(4,0, 64,65,66,67)  STASH_FRAG(4,1, 68,69,70,71)
    STASH_FRAG(4,2, 72,73,74,75)  STASH_FRAG(4,3, 76,77,78,79)
    STASH_FRAG(5,0, 80,81,82,83)  STASH_FRAG(5,1, 84,85,86,87)
    STASH_FRAG(5,2, 88,89,90,91)  STASH_FRAG(5,3, 92,93,94,95)
    STASH_FRAG(6,0, 96,97,98,99)  STASH_FRAG(6,1, 100,101,102,103)
    STASH_FRAG(6,2, 104,105,106,107) STASH_FRAG(6,3, 108,109,110,111)

    if (tid < 128) { h16[0][tid] = 0; h16[1][tid] = 0; }

    int my_tile = base + ((slot_sel < 7) ? slot_sel : 6);
    if (my_tile > 24) my_tile = 24;
    const int my_u = 4 * my_tile + g4;                 // 0..99
    const int my_po = 16 * my_tile + 4 * g4;           // pre offset (floats)
    const int ow_lim = (wave == 0) ? 7 : 6;
    const bool writer = (slot_sel < ow_lim) && ((lane & 8) == 0);

    int sicj[7], gqj[7]; bool okj[7];
    #pragma unroll
    for (int j = 0; j < 7; ++j) {
        int idx = tid + 256 * j;
        okj[j] = (idx < 1600);
        int ic = okj[j] ? idx : 0;
        sicj[j] = ic / 100;
        gqj[j] = ic - 100 * sicj[j];
    }

    float c = 0.f;
    f32x4 rr[7];

    LOADCHUNK(0)
    WRITECHUNK(0)
    LOADCHUNK(1)
    BAR();

    for (int k = 0; k < 16; ++k) {
        const int s0 = 16 * k;
        const int curbase = (k & 1) * 6400;
        LSTM_STEP(0)  LSTM_STEP(1)  LSTM_STEP(2)  LSTM_STEP(3)
        LSTM_STEP(4)  LSTM_STEP(5)  LSTM_STEP(6)  LSTM_STEP(7)
        LSTM_STEP(8)  LSTM_STEP(9)  LSTM_STEP(10) LSTM_STEP(11)
        LSTM_STEP(12) LSTM_STEP(13) LSTM_STEP(14) LSTM_STEP(15)
        if (k < 15) { WRITECHUNK((k & 1) ^ 1) }
        if (k < 14) { LOADCHUNK(k + 2) }
        BAR();
    }
}

// ---------------------------------------------------------------------------
// logits + log_softmax: one 32-lane half-wave per token.
// ---------------------------------------------------------------------------
__global__ __launch_bounds__(256) void logits_lsm(
    const float* __restrict__ h1,
    const float* __restrict__ out_w,
    const float* __restrict__ out_b,
    float* __restrict__ logits)
{
    const int lane = threadIdx.x & 63;
    const int wid = (blockIdx.x * 256 + threadIdx.x) >> 6;
    const int half = lane >> 5;
    const int n = lane & 31;
    const int i = wid * 2 + half;
    if (i >= NTOK) return;

    float acc = -1e30f;
    if (n < NTAGS) {
        acc = out_b[n];
        const float4* hr = (const float4*)(h1 + (size_t)i * 200);
        const float4* wr = (const float4*)(out_w + (size_t)n * 200);
        #pragma unroll
        for (int e = 0; e < 50; ++e) {
            float4 h4 = hr[e], w4 = wr[e];
            acc += h4.x * w4.x + h4.y * w4.y + h4.z * w4.z + h4.w * w4.w;
        }
    }
    float m = acc;
    for (int off = 16; off > 0; off >>= 1) m = fmaxf(m, __shfl_xor(m, off, 32));
    float ex = (n < NTAGS) ? __expf(acc - m) : 0.f;
    float s = ex;
    for (int off = 16; off > 0; off >>= 1) s += __shfl_xor(s, off, 32);
    if (n < NTAGS) logits[(size_t)i * NTAGS + n] = acc - m - __logf(s);
}

// ---------------------------------------------------------------------------
// CRF loss: one wave per batch element (R11 version).
// ---------------------------------------------------------------------------
__global__ __launch_bounds__(64) void crf_kernel(
    const float* __restrict__ logits,
    const int* __restrict__ words,
    const int* __restrict__ target,
    const float* __restrict__ trans,
    const float* __restrict__ start_s,
    const float* __restrict__ end_s,
    float* __restrict__ out)
{
    const int b = blockIdx.x;
    const int j = threadIdx.x;
    const int j21 = (j < NTAGS) ? j : (NTAGS - 1);

    float tcol[NTAGS];
    #pragma unroll
    for (int i = 0; i < NTAGS; ++i) tcol[i] = (j < NTAGS) ? trans[i * NTAGS + j] : 0.f;

    const int w0 = words[b * TT +   0 + j];
    const int w1 = words[b * TT +  64 + j];
    const int w2 = words[b * TT + 128 + j];
    const int w3 = words[b * TT + 192 + j];

    float alpha = (j < NTAGS) ? (logits[(size_t)(0 * BB + b) * NTAGS + j] + start_s[j]) : -1e30f;
    float e_cur = logits[(size_t)(1 * BB + b) * NTAGS + j21];

#define CRF_CHUNK(WREG, T0) \
    for (int u = ((T0) == 0 ? 1 : 0); u < 64; ++u) { \
        const int t = (T0) + u; \
        float e_nxt = 0.f; \
        if (t + 1 < TT) e_nxt = logits[(size_t)((t + 1) * BB + b) * NTAGS + j21]; \
        if (__shfl(WREG, u, 64) != 0) { \
            float v[NTAGS]; \
            _Pragma("unroll") \
            for (int i2 = 0; i2 < NTAGS; ++i2) \
                v[i2] = __shfl(alpha, i2, 64) + tcol[i2]; \
            float m0[11]; \
            _Pragma("unroll") \
            for (int p = 0; p < 10; ++p) m0[p] = fmaxf(v[2*p], v[2*p+1]); \
            m0[10] = v[20]; \
            float m1[6]; \
            _Pragma("unroll") \
            for (int p = 0; p < 5; ++p) m1[p] = fmaxf(m0[2*p], m0[2*p+1]); \
            m1[5] = m0[10]; \
            float m2a = fmaxf(m1[0], m1[1]), m2b = fmaxf(m1[2], m1[3]), m2c = fmaxf(m1[4], m1[5]); \
            float mx = fmaxf(fmaxf(m2a, m2b), m2c); \
            float e[NTAGS]; \
            _Pragma("unroll") \
            for (int i2 = 0; i2 < NTAGS; ++i2) e[i2] = __expf(v[i2] - mx); \
            float s0[11]; \
            _Pragma("unroll") \
            for (int p = 0; p < 10; ++p) s0[p] = e[2*p] + e[2*p+1]; \
            s0[10] = e[20]; \
            float s1[6]; \
            _Pragma("unroll") \
            for (int p = 0; p < 5; ++p) s1[p] = s0[2*p] + s0[2*p+1]; \
            s1[5] = s0[10]; \
            float ss = ((s1[0] + s1[1]) + (s1[2] + s1[3])) + (s1[4] + s1[5]); \
            float na = mx + __logf(ss) + e_cur; \
            alpha = (j < NTAGS) ? na : -1e30f; \
        } \
        e_cur = e_nxt; \
    }

    CRF_CHUNK(w0, 0)
    CRF_CHUNK(w1, 64)
    CRF_CHUNK(w2, 128)
    CRF_CHUNK(w3, 192)
#undef CRF_CHUNK

    float val = (j < NTAGS) ? (alpha + end_s[j]) : -1e30f;
    float mx = val;
    for (int off = 32; off > 0; off >>= 1) mx = fmaxf(mx, __shfl_xor(mx, off, 64));
    float s = (j < NTAGS) ? __expf(val - mx) : 0.f;
    for (int off = 32; off > 0; off >>= 1) s += __shfl_xor(s, off, 64);
    float norm = mx + __logf(s);

    float gold = 0.f, slen = 0.f;
    for (int t = j; t < TT; t += 64) {
        int tg = target[b * TT + t];
        bool m = (words[b * TT + t] != 0);
        if (m) {
            gold += logits[(size_t)(t * BB + b) * NTAGS + tg];
            slen += 1.f;
            if (t >= 1) gold += trans[target[b * TT + t - 1] * NTAGS + tg];
        }
    }
    for (int off = 32; off > 0; off >>= 1) {
        gold += __shfl_xor(gold, off, 64);
        slen += __shfl_xor(slen, off, 64);
    }
    if (j == 0) {
        int len = (int)slen;
        int last = (len > 0) ? (len - 1) : 0;
        int last_tag = target[b * TT + last];
        gold += start_s[target[b * TT + 0]] + end_s[last_tag];
        out[b] = norm - gold;
    }
}

// ---------------------------------------------------------------------------
extern "C" void kernel_launch(void* const* d_in, const int* in_sizes, int n_in,
                              void* d_out, int out_size, void* d_ws, size_t ws_size,
                              hipStream_t stream) {
    const int*   words   = (const int*)  d_in[0];
    const int*   target  = (const int*)  d_in[1];
    const float* embed   = (const float*)d_in[2];
    const float* in_fc_w = (const float*)d_in[3];
    const float* in_fc_b = (const float*)d_in[4];
    const float* Wih0    = (const float*)d_in[5];
    const float* Whh0    = (const float*)d_in[6];
    const float* bih0    = (const float*)d_in[7];
    const float* bhh0    = (const float*)d_in[8];
    const float* Wih1    = (const float*)d_in[9];
    const float* Whh1    = (const float*)d_in[10];
    const float* bih1    = (const float*)d_in[11];
    const float* bhh1    = (const float*)d_in[12];
    const float* out_w   = (const float*)d_in[13];
    const float* out_b   = (const float*)d_in[14];
    const float* trans   = (const float*)d_in[15];
    const float* start_s = (const float*)d_in[16];
    const float* end_s   = (const float*)d_in[17];
    float* out = (float*)d_out;

    float* ws = (float*)d_ws;
    // layout (floats): x [0,2097152)  pre [2097152,8650752)  h0 [8650752,10289152)
    //                  h1 = x region  logits [1638400,1810432)
    float* x      = ws;
    float* pre    = ws + 2097152;
    float* h0     = ws + 8650752;
    float* h1     = ws;
    float* logits = ws + 1638400;

    // 1) x = gather(embed, words) @ in_fc_w^T + in_fc_b     (8192 x 256)
    gemm_mfma<<<dim3(64, 4), 256, 0, stream>>>(
        embed, EMBED, in_fc_w, EMBED, in_fc_b, nullptr,
        x, DMODEL, DMODEL, EMBED, words, 0);

    // 2) pre0 = x @ Wih0^T (gate-permuted) + (bih0 + bhh0)  (8192 x 800)
    gemm_mfma<<<dim3(64, 13), 256, 0, stream>>>(
        x, DMODEL, Wih0, DMODEL, bih0, bhh0,
        pre, 800, 800, DMODEL, nullptr, 1);

    // 3) layer0 recurrence -> h0 (8192 x 200)
    lstm_mfma<<<64, 256, 0, stream>>>(pre, Whh0, h0);

    // 4) pre1 = h0 @ Wih1^T (gate-permuted) + (bih1 + bhh1) (8192 x 800)
    gemm_mfma<<<dim3(64, 13), 256, 0, stream>>>(
        h0, 200, Wih1, 200, bih1, bhh1,
        pre, 800, 800, 200, nullptr, 1);

    // 5) layer1 recurrence -> h1 (8192 x 200)
    lstm_mfma<<<64, 256, 0, stream>>>(pre, Whh1, h1);

    // 6) logits + log_softmax (8192 x 21)
    logits_lsm<<<NTOK / 8, 256, 0, stream>>>(h1, out_w, out_b, logits);

    // 7) CRF loss -> out (32)
    crf_kernel<<<BB, 64, 0, stream>>>(logits, words, target, trans, start_s, end_s, out);
}